// Round 1
// baseline (175.886 us; speedup 1.0000x reference)
//
#include <hip/hip_runtime.h>
#include <math.h>

#define NBINS 15

#if __has_builtin(__builtin_amdgcn_exp2f)
#define EXP2F __builtin_amdgcn_exp2f
#else
#define EXP2F exp2f
#endif

// ---------------------------------------------------------------------------
// Kernel 0: zero the 45-float bin accumulator in workspace (harness poisons
// d_ws with 0xAA and never re-poisons between replays -> must self-zero).
// ---------------------------------------------------------------------------
__global__ void ece_zero_bins(float* __restrict__ ws) {
    int t = threadIdx.x;
    if (t < NBINS * 3) ws[t] = 0.0f;
}

// ---------------------------------------------------------------------------
// Kernel 1: one wave (64 lanes) per row. Row = C floats (C<=1024), read as
// float4 chunks held in registers. Pass A: max + first-occurrence argmax.
// Pass B: sum of exp2((x - max) * log2e) from registers. Lane 0 bins the
// confidence and accumulates (count, sum_conf, sum_acc) into LDS; block
// flushes to global atomics at the end.
// ---------------------------------------------------------------------------
__global__ __launch_bounds__(256) void ece_phase1(
        const float* __restrict__ logits,
        const int*   __restrict__ labels,
        float*       __restrict__ ws,
        int N, int C) {
    __shared__ float s_cnt[NBINS];
    __shared__ float s_conf[NBINS];
    __shared__ float s_acc[NBINS];

    const int tid = threadIdx.x;
    if (tid < NBINS) { s_cnt[tid] = 0.0f; s_conf[tid] = 0.0f; s_acc[tid] = 0.0f; }
    __syncthreads();

    const int lane          = tid & 63;
    const int waveInBlock   = tid >> 6;
    const int wavesPerBlock = blockDim.x >> 6;
    const int waveId        = blockIdx.x * wavesPerBlock + waveInBlock;
    const int nWaves        = gridDim.x * wavesPerBlock;
    const int nchunk        = (C + 3) >> 2;          // float4 chunks per row

    const float L2E = 1.4426950408889634f;

    for (int row = waveId; row < N; row += nWaves) {
        const float4* rp = (const float4*)(logits + (size_t)row * (size_t)C);

        float4 v[4];
        float bestv = -INFINITY;
        int   besti = 0x7fffffff;

        #pragma unroll
        for (int j = 0; j < 4; ++j) {
            const int q  = lane + 64 * j;
            const bool ok = (q < nchunk);
            float4 x = make_float4(-INFINITY, -INFINITY, -INFINITY, -INFINITY);
            if (ok) x = rp[q];
            const int e0 = q << 2;
            // mask tail components of a partial last chunk
            if (ok) {
                if (e0 + 1 >= C) x.y = -INFINITY;
                if (e0 + 2 >= C) x.z = -INFINITY;
                if (e0 + 3 >= C) x.w = -INFINITY;
            }
            v[j] = x;
            // first-occurrence argmax within lane (elements visited in
            // increasing global index order for this lane)
            { bool g = x.x > bestv; bestv = g ? x.x : bestv; besti = g ? (e0    ) : besti; }
            { bool g = x.y > bestv; bestv = g ? x.y : bestv; besti = g ? (e0 + 1) : besti; }
            { bool g = x.z > bestv; bestv = g ? x.z : bestv; besti = g ? (e0 + 2) : besti; }
            { bool g = x.w > bestv; bestv = g ? x.w : bestv; besti = g ? (e0 + 3) : besti; }
        }

        // cross-lane (max, min-index-of-max) butterfly
        #pragma unroll
        for (int m = 32; m > 0; m >>= 1) {
            float ov = __shfl_xor(bestv, m, 64);
            int   oi = __shfl_xor(besti, m, 64);
            bool take = (ov > bestv) || ((ov == bestv) && (oi < besti));
            bestv = take ? ov : bestv;
            besti = take ? oi : besti;
        }
        // bestv/besti now wave-uniform: row max and argmax

        // sum of exp(x - max) (invalid lanes/components are -INF -> exp 0)
        const float c0 = -bestv * L2E;
        float s = 0.0f;
        #pragma unroll
        for (int j = 0; j < 4; ++j) {
            s += EXP2F(fmaf(v[j].x, L2E, c0));
            s += EXP2F(fmaf(v[j].y, L2E, c0));
            s += EXP2F(fmaf(v[j].z, L2E, c0));
            s += EXP2F(fmaf(v[j].w, L2E, c0));
        }
        #pragma unroll
        for (int m = 32; m > 0; m >>= 1) s += __shfl_xor(s, m, 64);

        if (lane == 0) {
            const float conf = 1.0f / s;   // max prob = exp(0)/sum
            // bin: first b with conf <= bounds[b+1]  (== reference semantics:
            // conf > bounds[b] && conf <= bounds[b+1], since bins partition (0,1])
            int b = NBINS - 1;
            #pragma unroll
            for (int i = 0; i < NBINS; ++i) {
                float ub = (float)((double)(i + 1) / (double)NBINS);
                if (conf <= ub) { b = i; break; }
            }
            const int lab = labels[row];
            atomicAdd(&s_cnt[b],  1.0f);
            atomicAdd(&s_conf[b], conf);
            atomicAdd(&s_acc[b],  (besti == lab) ? 1.0f : 0.0f);
        }
    }

    __syncthreads();
    if (tid < NBINS) {
        atomicAdd(&ws[tid],             s_cnt[tid]);
        atomicAdd(&ws[NBINS + tid],     s_conf[tid]);
        atomicAdd(&ws[2 * NBINS + tid], s_acc[tid]);
    }
}

// ---------------------------------------------------------------------------
// Kernel 2: scalar epilogue -> 100 * ECE
// ---------------------------------------------------------------------------
__global__ void ece_phase2(const float* __restrict__ ws,
                           float* __restrict__ out, int N) {
    if (threadIdx.x == 0 && blockIdx.x == 0) {
        float ece = 0.0f;
        for (int i = 0; i < NBINS; ++i) {
            float cnt = ws[i];
            float sc  = ws[NBINS + i];
            float sa  = ws[2 * NBINS + i];
            float safe = fmaxf(cnt, 1.0f);
            float gap  = fabsf(sc / safe - sa / safe);
            if (cnt > 0.0f) ece += gap * (cnt / (float)N);
        }
        out[0] = 100.0f * ece;
    }
}

extern "C" void kernel_launch(void* const* d_in, const int* in_sizes, int n_in,
                              void* d_out, int out_size, void* d_ws, size_t ws_size,
                              hipStream_t stream) {
    const int*   labels = (const int*)d_in[0];
    const float* logits = (const float*)d_in[1];
    float*       out    = (float*)d_out;
    float*       ws     = (float*)d_ws;

    const int N = in_sizes[0];
    const int C = in_sizes[1] / in_sizes[0];   // 1000

    ece_zero_bins<<<1, 64, 0, stream>>>(ws);

    const int block = 256;
    const int grid  = 2048;                    // 8192 waves -> 16 rows/wave
    ece_phase1<<<grid, block, 0, stream>>>(logits, labels, ws, N, C);

    ece_phase2<<<1, 64, 0, stream>>>(ws, out, N);
}

// Round 2
// 134.642 us; speedup vs baseline: 1.3063x; 1.3063x over previous
//
#include <hip/hip_runtime.h>
#include <math.h>

#define NBINS 15

#if __has_builtin(__builtin_amdgcn_exp2f)
#define EXP2F __builtin_amdgcn_exp2f
#else
#define EXP2F exp2f
#endif

// ---------------------------------------------------------------------------
// Kernel 0: zero the 45-float bin accumulator in workspace (harness poisons
// d_ws with 0xAA and never re-poisons between replays -> must self-zero).
// ---------------------------------------------------------------------------
__global__ void ece_zero_bins(float* __restrict__ ws) {
    int t = threadIdx.x;
    if (t < NBINS * 3) ws[t] = 0.0f;
}

// ---------------------------------------------------------------------------
// Kernel 1: one wave (64 lanes) per row, 2-deep software pipeline over rows.
// While row i's reductions/exp run, row i+1's 4 KB is already in flight.
// ---------------------------------------------------------------------------
__global__ __launch_bounds__(256) void ece_phase1(
        const float* __restrict__ logits,
        const int*   __restrict__ labels,
        float*       __restrict__ ws,
        int N, int C) {
    __shared__ float s_cnt[NBINS];
    __shared__ float s_conf[NBINS];
    __shared__ float s_acc[NBINS];

    const int tid = threadIdx.x;
    if (tid < NBINS) { s_cnt[tid] = 0.0f; s_conf[tid] = 0.0f; s_acc[tid] = 0.0f; }
    __syncthreads();

    const int lane          = tid & 63;
    const int waveInBlock   = tid >> 6;
    const int wavesPerBlock = blockDim.x >> 6;
    const int waveId        = blockIdx.x * wavesPerBlock + waveInBlock;
    const int nWaves        = gridDim.x * wavesPerBlock;
    const int nchunk        = (C + 3) >> 2;          // float4 chunks per row

    const float L2E = 1.4426950408889634f;

    float4 cur[4], nxt[4];
    int row  = waveId;
    bool have = (row < N);
    int lab  = 0;

    // prologue: load row 0's chunks + label
    if (have) {
        const float4* rp = (const float4*)(logits + (size_t)row * (size_t)C);
        #pragma unroll
        for (int j = 0; j < 4; ++j) {
            const int q = lane + 64 * j;
            float4 x = make_float4(-INFINITY, -INFINITY, -INFINITY, -INFINITY);
            if (q < nchunk) x = rp[q];
            cur[j] = x;
        }
        lab = labels[row];
    }

    while (have) {
        // ---- issue next row's loads FIRST (stay in flight during compute) ----
        const int  nrow  = row + nWaves;
        const bool hnext = (nrow < N);
        int nlab = 0;
        #pragma unroll
        for (int j = 0; j < 4; ++j) {
            const int q = lane + 64 * j;
            float4 x = make_float4(-INFINITY, -INFINITY, -INFINITY, -INFINITY);
            if (hnext && q < nchunk)
                x = ((const float4*)(logits + (size_t)nrow * (size_t)C))[q];
            nxt[j] = x;
        }
        if (hnext) nlab = labels[nrow];

        // ---- process current row ----
        float bestv = -INFINITY;
        int   besti = 0x7fffffff;
        #pragma unroll
        for (int j = 0; j < 4; ++j) {
            const int e0 = (lane + 64 * j) << 2;
            { bool g = cur[j].x > bestv; bestv = g ? cur[j].x : bestv; besti = g ? (e0    ) : besti; }
            { bool g = cur[j].y > bestv; bestv = g ? cur[j].y : bestv; besti = g ? (e0 + 1) : besti; }
            { bool g = cur[j].z > bestv; bestv = g ? cur[j].z : bestv; besti = g ? (e0 + 2) : besti; }
            { bool g = cur[j].w > bestv; bestv = g ? cur[j].w : bestv; besti = g ? (e0 + 3) : besti; }
        }

        // cross-lane (max, min-index-of-max) butterfly
        #pragma unroll
        for (int m = 32; m > 0; m >>= 1) {
            float ov = __shfl_xor(bestv, m, 64);
            int   oi = __shfl_xor(besti, m, 64);
            bool take = (ov > bestv) || ((ov == bestv) && (oi < besti));
            bestv = take ? ov : bestv;
            besti = take ? oi : besti;
        }

        // sum of exp(x - max); masked components are -INF -> contribute 0
        const float c0 = -bestv * L2E;
        float s = 0.0f;
        #pragma unroll
        for (int j = 0; j < 4; ++j) {
            s += EXP2F(fmaf(cur[j].x, L2E, c0));
            s += EXP2F(fmaf(cur[j].y, L2E, c0));
            s += EXP2F(fmaf(cur[j].z, L2E, c0));
            s += EXP2F(fmaf(cur[j].w, L2E, c0));
        }
        #pragma unroll
        for (int m = 32; m > 0; m >>= 1) s += __shfl_xor(s, m, 64);

        if (lane == 0) {
            const float conf = 1.0f / s;   // max prob
            int b = NBINS - 1;
            #pragma unroll
            for (int i = 0; i < NBINS; ++i) {
                float ub = (float)((double)(i + 1) / (double)NBINS);
                if (conf <= ub) { b = i; break; }
            }
            atomicAdd(&s_cnt[b],  1.0f);
            atomicAdd(&s_conf[b], conf);
            atomicAdd(&s_acc[b],  (besti == lab) ? 1.0f : 0.0f);
        }

        // ---- rotate pipeline ----
        #pragma unroll
        for (int j = 0; j < 4; ++j) cur[j] = nxt[j];
        lab  = nlab;
        row  = nrow;
        have = hnext;
    }

    __syncthreads();
    if (tid < NBINS) {
        atomicAdd(&ws[tid],             s_cnt[tid]);
        atomicAdd(&ws[NBINS + tid],     s_conf[tid]);
        atomicAdd(&ws[2 * NBINS + tid], s_acc[tid]);
    }
}

// ---------------------------------------------------------------------------
// Kernel 2: scalar epilogue -> 100 * ECE
// ---------------------------------------------------------------------------
__global__ void ece_phase2(const float* __restrict__ ws,
                           float* __restrict__ out, int N) {
    if (threadIdx.x == 0 && blockIdx.x == 0) {
        float ece = 0.0f;
        for (int i = 0; i < NBINS; ++i) {
            float cnt = ws[i];
            float sc  = ws[NBINS + i];
            float sa  = ws[2 * NBINS + i];
            float safe = fmaxf(cnt, 1.0f);
            float gap  = fabsf(sc / safe - sa / safe);
            if (cnt > 0.0f) ece += gap * (cnt / (float)N);
        }
        out[0] = 100.0f * ece;
    }
}

extern "C" void kernel_launch(void* const* d_in, const int* in_sizes, int n_in,
                              void* d_out, int out_size, void* d_ws, size_t ws_size,
                              hipStream_t stream) {
    const int*   labels = (const int*)d_in[0];
    const float* logits = (const float*)d_in[1];
    float*       out    = (float*)d_out;
    float*       ws     = (float*)d_ws;

    const int N = in_sizes[0];
    const int C = in_sizes[1] / in_sizes[0];   // 1000

    ece_zero_bins<<<1, 64, 0, stream>>>(ws);

    const int block = 256;
    const int grid  = 2048;                    // 8192 waves -> 16 rows/wave
    ece_phase1<<<grid, block, 0, stream>>>(logits, labels, ws, N, C);

    ece_phase2<<<1, 64, 0, stream>>>(ws, out, N);
}

// Round 3
// 124.037 us; speedup vs baseline: 1.4180x; 1.0855x over previous
//
#include <hip/hip_runtime.h>
#include <math.h>

#define NBINS 15

__device__ __forceinline__ float exp2_fast(float x) {
#if __has_builtin(__builtin_amdgcn_exp2f)
    return __builtin_amdgcn_exp2f(x);
#else
    return exp2f(x);
#endif
}

// ---------------------------------------------------------------------------
// Kernel 0: zero the 45-float bin accumulator (d_ws poisoned 0xAA, never
// re-poisoned between replays -> must self-zero each call).
// ---------------------------------------------------------------------------
__global__ void ece_zero_bins(float* __restrict__ ws) {
    int t = threadIdx.x;
    if (t < NBINS * 3) ws[t] = 0.0f;
}

// ---------------------------------------------------------------------------
// Kernel 1: one wave per row, manual 2-deep ping-pong pipeline.
// Loads are UNCONDITIONAL (chunk index clamped in-bounds) so the compiler can
// defer the vmcnt wait to first use -> prefetch stays in flight over compute.
// Accuracy via (label element == rowmax) + __ballot: no argmax tracking.
// ---------------------------------------------------------------------------
__global__ __launch_bounds__(256) void ece_phase1(
        const float* __restrict__ logits,
        const int*   __restrict__ labels,
        float*       __restrict__ ws,
        int N, int C) {
    __shared__ float s_cnt[NBINS];
    __shared__ float s_conf[NBINS];
    __shared__ float s_acc[NBINS];

    const int tid = threadIdx.x;
    if (tid < NBINS) { s_cnt[tid] = 0.0f; s_conf[tid] = 0.0f; s_acc[tid] = 0.0f; }
    __syncthreads();

    const int lane   = tid & 63;
    const int wib    = tid >> 6;
    const int wpb    = blockDim.x >> 6;
    const int waveId = blockIdx.x * wpb + wib;
    const int nWaves = gridDim.x * wpb;
    const int nchunk = C >> 2;              // C % 4 == 0 (C = 1000 -> 250)
    const float L2E  = 1.4426950408889634f;

    // per-j lane validity (whole-chunk): lane < vl[j] owns a real chunk
    int vl[4];
    #pragma unroll
    for (int j = 0; j < 4; ++j) {
        int v = nchunk - 64 * j;
        vl[j] = v < 0 ? 0 : (v > 64 ? 64 : v);
    }

    // ---- unconditional row load: clamp chunk index in-bounds ----
    auto loadrow = [&](float4* v, int r, int& lab) {
        const float4* rp = (const float4*)(logits + (size_t)r * (size_t)C);
        #pragma unroll
        for (int j = 0; j < 4; ++j) {
            int q = lane + 64 * j;
            q = (q < nchunk) ? q : (nchunk - 1);   // duplicate of in-row data
            v[j] = rp[q];
        }
        lab = labels[r];
    };

    auto compute = [&](const float4* v, int lab) {
        // row max: clamped duplicates are in-row values -> no masking needed
        float m = fmaxf(fmaxf(v[0].x, v[0].y), fmaxf(v[0].z, v[0].w));
        #pragma unroll
        for (int j = 1; j < 4; ++j)
            m = fmaxf(m, fmaxf(fmaxf(v[j].x, v[j].y), fmaxf(v[j].z, v[j].w)));
        #pragma unroll
        for (int msk = 32; msk; msk >>= 1) m = fmaxf(m, __shfl_xor(m, msk, 64));

        // sum(exp(x - m)); mask duplicated tail chunks
        const float c0 = -m * L2E;
        float s = 0.0f;
        #pragma unroll
        for (int j = 0; j < 4; ++j) {
            float sj = exp2_fast(fmaf(v[j].x, L2E, c0))
                     + exp2_fast(fmaf(v[j].y, L2E, c0))
                     + exp2_fast(fmaf(v[j].z, L2E, c0))
                     + exp2_fast(fmaf(v[j].w, L2E, c0));
            s += (lane < vl[j]) ? sj : 0.0f;
        }
        #pragma unroll
        for (int msk = 32; msk; msk >>= 1) s += __shfl_xor(s, msk, 64);

        // accuracy: label's element equals the row max?
        // (clamped lanes have nominal e0 >= C > lab -> automatically excluded)
        bool pred = false;
        #pragma unroll
        for (int j = 0; j < 4; ++j) {
            const int e0 = (lane + 64 * j) << 2;
            const int d  = lab - e0;
            if ((unsigned)d < 4u) {
                float val = (d == 0) ? v[j].x : (d == 1) ? v[j].y
                          : (d == 2) ? v[j].z : v[j].w;
                pred = (val == m);
            }
        }
        const bool hit = (__ballot(pred) != 0ull);

        if (lane == 0) {
            const float conf = 1.0f / s;
            int b = NBINS - 1;
            #pragma unroll
            for (int i = 0; i < NBINS; ++i) {
                float ub = (float)((double)(i + 1) / (double)NBINS);
                if (conf <= ub) { b = i; break; }
            }
            atomicAdd(&s_cnt[b],  1.0f);
            atomicAdd(&s_conf[b], conf);
            atomicAdd(&s_acc[b],  hit ? 1.0f : 0.0f);
        }
    };

    float4 A[4], B[4];
    int labA = 0, labB = 0;

    int row = waveId;                        // wave-uniform
    if (row < N) loadrow(A, row, labA);
    while (row < N) {
        const int rowB = row + nWaves;
        if (rowB < N) loadrow(B, rowB, labB);     // uniform branch: no lane mask
        compute(A, labA);
        if (rowB >= N) break;
        const int rowA = rowB + nWaves;
        if (rowA < N) loadrow(A, rowA, labA);
        compute(B, labB);
        row = rowA;
    }

    __syncthreads();
    if (tid < NBINS) {
        atomicAdd(&ws[tid],             s_cnt[tid]);
        atomicAdd(&ws[NBINS + tid],     s_conf[tid]);
        atomicAdd(&ws[2 * NBINS + tid], s_acc[tid]);
    }
}

// ---------------------------------------------------------------------------
// Kernel 2: scalar epilogue -> 100 * ECE
// ---------------------------------------------------------------------------
__global__ void ece_phase2(const float* __restrict__ ws,
                           float* __restrict__ out, int N) {
    if (threadIdx.x == 0 && blockIdx.x == 0) {
        float ece = 0.0f;
        for (int i = 0; i < NBINS; ++i) {
            float cnt = ws[i];
            float sc  = ws[NBINS + i];
            float sa  = ws[2 * NBINS + i];
            float safe = fmaxf(cnt, 1.0f);
            float gap  = fabsf(sc / safe - sa / safe);
            if (cnt > 0.0f) ece += gap * (cnt / (float)N);
        }
        out[0] = 100.0f * ece;
    }
}

extern "C" void kernel_launch(void* const* d_in, const int* in_sizes, int n_in,
                              void* d_out, int out_size, void* d_ws, size_t ws_size,
                              hipStream_t stream) {
    const int*   labels = (const int*)d_in[0];
    const float* logits = (const float*)d_in[1];
    float*       out    = (float*)d_out;
    float*       ws     = (float*)d_ws;

    const int N = in_sizes[0];
    const int C = in_sizes[1] / in_sizes[0];   // 1000

    ece_zero_bins<<<1, 64, 0, stream>>>(ws);

    const int block = 256;
    const int grid  = 2048;                    // 8192 waves -> 16 rows/wave
    ece_phase1<<<grid, block, 0, stream>>>(logits, labels, ws, N, C);

    ece_phase2<<<1, 64, 0, stream>>>(ws, out, N);
}

// Round 4
// 122.551 us; speedup vs baseline: 1.4352x; 1.0121x over previous
//
#include <hip/hip_runtime.h>
#include <math.h>

#define NBINS 15

__device__ __forceinline__ float exp2_fast(float x) {
#if __has_builtin(__builtin_amdgcn_exp2f)
    return __builtin_amdgcn_exp2f(x);
#else
    return exp2f(x);
#endif
}

// ---------------------------------------------------------------------------
// Kernel 0: zero the 45-float bin accumulator (d_ws poisoned 0xAA, never
// re-poisoned between replays -> must self-zero each call).
// ---------------------------------------------------------------------------
__global__ void ece_zero_bins(float* __restrict__ ws) {
    int t = threadIdx.x;
    if (t < NBINS * 3) ws[t] = 0.0f;
}

// ---------------------------------------------------------------------------
// Kernel 1: one wave per row, 3-deep rotating pipeline (prefetch 2 rows
// ahead: ~1400 cyc of compute covers the ~900 cyc HBM latency, vs ~700 at
// depth 2 -> removes the ~200-cyc per-row wave stall).
// NCHUNK_CT: compile-time chunk count (250 for C=1000), 0 = runtime-generic.
// ---------------------------------------------------------------------------
template<int NCHUNK_CT>
__global__ __launch_bounds__(256) void ece_phase1(
        const float* __restrict__ logits,
        const int*   __restrict__ labels,
        float*       __restrict__ ws,
        int N, int C) {
    __shared__ float s_cnt[NBINS];
    __shared__ float s_conf[NBINS];
    __shared__ float s_acc[NBINS];

    const int tid = threadIdx.x;
    if (tid < NBINS) { s_cnt[tid] = 0.0f; s_conf[tid] = 0.0f; s_acc[tid] = 0.0f; }
    __syncthreads();

    const int lane   = tid & 63;
    const int wib    = tid >> 6;
    const int wpb    = blockDim.x >> 6;
    const int waveId = blockIdx.x * wpb + wib;
    const int nWaves = gridDim.x * wpb;
    const int nchunk = NCHUNK_CT ? NCHUNK_CT : (C >> 2);
    const float L2E  = 1.4426950408889634f;

    // per-j lane validity (whole-chunk): lane < vl[j] owns a real chunk
    int vl[4];
    #pragma unroll
    for (int j = 0; j < 4; ++j) {
        int v = nchunk - 64 * j;
        vl[j] = v < 0 ? 0 : (v > 64 ? 64 : v);
    }

    // unconditional row load: clamp chunk index in-bounds (duplicates in-row
    // data; cannot change the row max, masked out of the exp-sum)
    auto loadrow = [&](float4* v, int r, int& lab) {
        const float4* rp = (const float4*)(logits + (size_t)r * (size_t)C);
        #pragma unroll
        for (int j = 0; j < 4; ++j) {
            int q = lane + 64 * j;
            q = (q < nchunk) ? q : (nchunk - 1);
            v[j] = rp[q];
        }
        lab = labels[r];
    };

    auto compute = [&](const float4* v, int lab) {
        float m = fmaxf(fmaxf(v[0].x, v[0].y), fmaxf(v[0].z, v[0].w));
        #pragma unroll
        for (int j = 1; j < 4; ++j)
            m = fmaxf(m, fmaxf(fmaxf(v[j].x, v[j].y), fmaxf(v[j].z, v[j].w)));
        #pragma unroll
        for (int msk = 32; msk; msk >>= 1) m = fmaxf(m, __shfl_xor(m, msk, 64));

        const float c0 = -m * L2E;
        float s = 0.0f;
        #pragma unroll
        for (int j = 0; j < 4; ++j) {
            float sj = exp2_fast(fmaf(v[j].x, L2E, c0))
                     + exp2_fast(fmaf(v[j].y, L2E, c0))
                     + exp2_fast(fmaf(v[j].z, L2E, c0))
                     + exp2_fast(fmaf(v[j].w, L2E, c0));
            // compile-time: full chunks (vl==64) need no mask
            if (NCHUNK_CT ? (vl[j] < 64) : true)
                sj = (lane < vl[j]) ? sj : 0.0f;
            s += sj;
        }
        #pragma unroll
        for (int msk = 32; msk; msk >>= 1) s += __shfl_xor(s, msk, 64);

        // accuracy: label's element equals the row max? (clamped lanes have
        // nominal e0 >= C > lab -> automatically excluded)
        bool pred = false;
        #pragma unroll
        for (int j = 0; j < 4; ++j) {
            const int e0 = (lane + 64 * j) << 2;
            const int d  = lab - e0;
            if ((unsigned)d < 4u) {
                float val = (d == 0) ? v[j].x : (d == 1) ? v[j].y
                          : (d == 2) ? v[j].z : v[j].w;
                pred = (val == m);
            }
        }
        const bool hit = (__ballot(pred) != 0ull);

        if (lane == 0) {
            const float conf = 1.0f / s;
            int b = NBINS - 1;
            #pragma unroll
            for (int i = 0; i < NBINS; ++i) {
                float ub = (float)((double)(i + 1) / (double)NBINS);
                if (conf <= ub) { b = i; break; }
            }
            atomicAdd(&s_cnt[b],  1.0f);
            atomicAdd(&s_conf[b], conf);
            atomicAdd(&s_acc[b],  hit ? 1.0f : 0.0f);
        }
    };

    float4 A[4], B[4], Cb[4];
    int labA = 0, labB = 0, labC = 0;

    int  ra = waveId, rb = ra + nWaves;
    bool hA = (ra < N), hB = (rb < N);
    if (hA) loadrow(A, ra, labA);
    if (hB) loadrow(B, rb, labB);

    while (hA) {
        const int  rc = rb + nWaves; const bool hC = (rc < N);
        if (hC) loadrow(Cb, rc, labC);
        compute(A, labA);
        if (!hB) break;

        const int  rd = rc + nWaves; const bool hD = (rd < N);
        if (hD) loadrow(A, rd, labA);
        compute(B, labB);
        if (!hC) break;

        const int  re = rd + nWaves; const bool hE = (re < N);
        if (hE) loadrow(B, re, labB);
        compute(Cb, labC);
        if (!hD) break;

        ra = rd; rb = re; hA = hD; hB = hE;
    }

    __syncthreads();
    if (tid < NBINS) {
        atomicAdd(&ws[tid],             s_cnt[tid]);
        atomicAdd(&ws[NBINS + tid],     s_conf[tid]);
        atomicAdd(&ws[2 * NBINS + tid], s_acc[tid]);
    }
}

// ---------------------------------------------------------------------------
// Kernel 2: scalar epilogue -> 100 * ECE
// ---------------------------------------------------------------------------
__global__ void ece_phase2(const float* __restrict__ ws,
                           float* __restrict__ out, int N) {
    if (threadIdx.x == 0 && blockIdx.x == 0) {
        float ece = 0.0f;
        for (int i = 0; i < NBINS; ++i) {
            float cnt = ws[i];
            float sc  = ws[NBINS + i];
            float sa  = ws[2 * NBINS + i];
            float safe = fmaxf(cnt, 1.0f);
            float gap  = fabsf(sc / safe - sa / safe);
            if (cnt > 0.0f) ece += gap * (cnt / (float)N);
        }
        out[0] = 100.0f * ece;
    }
}

extern "C" void kernel_launch(void* const* d_in, const int* in_sizes, int n_in,
                              void* d_out, int out_size, void* d_ws, size_t ws_size,
                              hipStream_t stream) {
    const int*   labels = (const int*)d_in[0];
    const float* logits = (const float*)d_in[1];
    float*       out    = (float*)d_out;
    float*       ws     = (float*)d_ws;

    const int N = in_sizes[0];
    const int C = in_sizes[1] / in_sizes[0];   // 1000

    ece_zero_bins<<<1, 64, 0, stream>>>(ws);

    const int block = 256;
    const int grid  = 2048;
    if (C == 1000)
        ece_phase1<250><<<grid, block, 0, stream>>>(logits, labels, ws, N, C);
    else
        ece_phase1<0><<<grid, block, 0, stream>>>(logits, labels, ws, N, C);

    ece_phase2<<<1, 64, 0, stream>>>(ws, out, N);
}

// Round 5
// 105.694 us; speedup vs baseline: 1.6641x; 1.1595x over previous
//
#include <hip/hip_runtime.h>
#include <math.h>

#define NBINS 15
#define NGRP  (NBINS * 3)      // 45 partial groups: [cnt | conf | acc] x 15 bins

__device__ __forceinline__ float exp2_fast(float x) {
#if __has_builtin(__builtin_amdgcn_exp2f)
    return __builtin_amdgcn_exp2f(x);
#else
    return exp2f(x);
#endif
}

// ---------------------------------------------------------------------------
// Kernel 1: one wave per row, 3-deep rotating pipeline. Per-block bin partials
// in LDS; flushed with PLAIN stores to ws[group*NB + blockIdx.x] (no global
// atomics -> no serialized RMW storm when all co-resident blocks finish
// together). Every slot is written every call -> no pre-zero kernel needed.
// ---------------------------------------------------------------------------
template<int NCHUNK_CT>
__global__ __launch_bounds__(256) void ece_phase1(
        const float* __restrict__ logits,
        const int*   __restrict__ labels,
        float*       __restrict__ ws,
        int N, int C, int NB) {
    __shared__ float s_cnt[NBINS];
    __shared__ float s_conf[NBINS];
    __shared__ float s_acc[NBINS];

    const int tid = threadIdx.x;
    if (tid < NBINS) { s_cnt[tid] = 0.0f; s_conf[tid] = 0.0f; s_acc[tid] = 0.0f; }
    __syncthreads();

    const int lane   = tid & 63;
    const int wib    = tid >> 6;
    const int wpb    = blockDim.x >> 6;
    const int waveId = blockIdx.x * wpb + wib;
    const int nWaves = gridDim.x * wpb;
    const int nchunk = NCHUNK_CT ? NCHUNK_CT : (C >> 2);
    const float L2E  = 1.4426950408889634f;

    int vl[4];
    #pragma unroll
    for (int j = 0; j < 4; ++j) {
        int v = nchunk - 64 * j;
        vl[j] = v < 0 ? 0 : (v > 64 ? 64 : v);
    }

    // unconditional row load: clamp chunk index in-bounds (duplicates in-row
    // data; cannot change the row max, masked out of the exp-sum)
    auto loadrow = [&](float4* v, int r, int& lab) {
        const float4* rp = (const float4*)(logits + (size_t)r * (size_t)C);
        #pragma unroll
        for (int j = 0; j < 4; ++j) {
            int q = lane + 64 * j;
            q = (q < nchunk) ? q : (nchunk - 1);
            v[j] = rp[q];
        }
        lab = labels[r];
    };

    auto compute = [&](const float4* v, int lab) {
        float m = fmaxf(fmaxf(v[0].x, v[0].y), fmaxf(v[0].z, v[0].w));
        #pragma unroll
        for (int j = 1; j < 4; ++j)
            m = fmaxf(m, fmaxf(fmaxf(v[j].x, v[j].y), fmaxf(v[j].z, v[j].w)));
        #pragma unroll
        for (int msk = 32; msk; msk >>= 1) m = fmaxf(m, __shfl_xor(m, msk, 64));

        const float c0 = -m * L2E;
        float s = 0.0f;
        #pragma unroll
        for (int j = 0; j < 4; ++j) {
            float sj = exp2_fast(fmaf(v[j].x, L2E, c0))
                     + exp2_fast(fmaf(v[j].y, L2E, c0))
                     + exp2_fast(fmaf(v[j].z, L2E, c0))
                     + exp2_fast(fmaf(v[j].w, L2E, c0));
            if (NCHUNK_CT ? (vl[j] < 64) : true)
                sj = (lane < vl[j]) ? sj : 0.0f;
            s += sj;
        }
        #pragma unroll
        for (int msk = 32; msk; msk >>= 1) s += __shfl_xor(s, msk, 64);

        // accuracy: does the label's element equal the row max?
        bool pred = false;
        #pragma unroll
        for (int j = 0; j < 4; ++j) {
            const int e0 = (lane + 64 * j) << 2;
            const int d  = lab - e0;
            if ((unsigned)d < 4u) {
                float val = (d == 0) ? v[j].x : (d == 1) ? v[j].y
                          : (d == 2) ? v[j].z : v[j].w;
                pred = (val == m);
            }
        }
        const bool hit = (__ballot(pred) != 0ull);

        if (lane == 0) {
            const float conf = 1.0f / s;
            int b = NBINS - 1;
            #pragma unroll
            for (int i = 0; i < NBINS; ++i) {
                float ub = (float)((double)(i + 1) / (double)NBINS);
                if (conf <= ub) { b = i; break; }
            }
            atomicAdd(&s_cnt[b],  1.0f);
            atomicAdd(&s_conf[b], conf);
            atomicAdd(&s_acc[b],  hit ? 1.0f : 0.0f);
        }
    };

    float4 A[4], B[4], Cb[4];
    int labA = 0, labB = 0, labC = 0;

    int  ra = waveId, rb = ra + nWaves;
    bool hA = (ra < N), hB = (rb < N);
    if (hA) loadrow(A, ra, labA);
    if (hB) loadrow(B, rb, labB);

    while (hA) {
        const int  rc = rb + nWaves; const bool hC = (rc < N);
        if (hC) loadrow(Cb, rc, labC);
        compute(A, labA);
        if (!hB) break;

        const int  rd = rc + nWaves; const bool hD = (rd < N);
        if (hD) loadrow(A, rd, labA);
        compute(B, labB);
        if (!hC) break;

        const int  re = rd + nWaves; const bool hE = (re < N);
        if (hE) loadrow(B, re, labB);
        compute(Cb, labC);
        if (!hD) break;

        ra = rd; rb = re; hA = hD; hB = hE;
    }

    __syncthreads();
    // plain per-block partial store: group g = stat*NBINS+bin, slot = blockIdx
    if (tid < NGRP) {
        const int stat = tid / NBINS;
        const int bin  = tid % NBINS;
        const float v  = (stat == 0) ? s_cnt[bin]
                       : (stat == 1) ? s_conf[bin] : s_acc[bin];
        ws[(size_t)tid * (size_t)NB + (size_t)blockIdx.x] = v;
    }
}

// ---------------------------------------------------------------------------
// Kernel 2: 45 blocks; block g sums its NB partials -> sums[g] = ws[NGRP*NB+g]
// ---------------------------------------------------------------------------
__global__ __launch_bounds__(256) void ece_phase2(
        const float* __restrict__ ws, float* __restrict__ sums, int NB) {
    __shared__ float s_w[4];
    const int g    = blockIdx.x;
    const int tid  = threadIdx.x;
    const int lane = tid & 63;
    const int wib  = tid >> 6;

    const float* p = ws + (size_t)g * (size_t)NB;
    float s = 0.0f;
    for (int i = tid; i < NB; i += 256) s += p[i];
    #pragma unroll
    for (int msk = 32; msk; msk >>= 1) s += __shfl_xor(s, msk, 64);
    if (lane == 0) s_w[wib] = s;
    __syncthreads();
    if (tid == 0) sums[g] = s_w[0] + s_w[1] + s_w[2] + s_w[3];
}

// ---------------------------------------------------------------------------
// Kernel 3: scalar epilogue -> 100 * ECE
// ---------------------------------------------------------------------------
__global__ void ece_phase3(const float* __restrict__ sums,
                           float* __restrict__ out, int N) {
    if (threadIdx.x == 0 && blockIdx.x == 0) {
        float ece = 0.0f;
        for (int i = 0; i < NBINS; ++i) {
            float cnt = sums[i];
            float sc  = sums[NBINS + i];
            float sa  = sums[2 * NBINS + i];
            float safe = fmaxf(cnt, 1.0f);
            float gap  = fabsf(sc / safe - sa / safe);
            if (cnt > 0.0f) ece += gap * (cnt / (float)N);
        }
        out[0] = 100.0f * ece;
    }
}

extern "C" void kernel_launch(void* const* d_in, const int* in_sizes, int n_in,
                              void* d_out, int out_size, void* d_ws, size_t ws_size,
                              hipStream_t stream) {
    const int*   labels = (const int*)d_in[0];
    const float* logits = (const float*)d_in[1];
    float*       out    = (float*)d_out;
    float*       ws     = (float*)d_ws;

    const int N = in_sizes[0];
    const int C = in_sizes[1] / in_sizes[0];   // 1000

    // blocks: 2048 if workspace allows (needs (NGRP*NB + NGRP) floats)
    int NB = 2048;
    while (NB > 64 && (size_t)(NGRP * NB + NGRP) * sizeof(float) > ws_size)
        NB >>= 1;
    float* sums = ws + (size_t)NGRP * (size_t)NB;

    if (C == 1000)
        ece_phase1<250><<<NB, 256, 0, stream>>>(logits, labels, ws, N, C, NB);
    else
        ece_phase1<0><<<NB, 256, 0, stream>>>(logits, labels, ws, N, C, NB);

    ece_phase2<<<NGRP, 256, 0, stream>>>(ws, sums, NB);
    ece_phase3<<<1, 64, 0, stream>>>(sums, out, N);
}